// Round 7
// baseline (407.726 us; speedup 1.0000x reference)
//
#include <hip/hip_runtime.h>

// AdultConnectomeNetwork: 3 layers of xt = A_sp @ (W_sp @ xt) + bias.
// Round 22: replace the 5-kernel LDS-staged counting sort (pass1 44us @r19,
// pass2 ~20us, hist ~15us, scans ~10us -> ~90us total) with a trivial
// global-atomic scatter chain (~30us): zero -> rowcnt hist (1.6M global
// atomics on 50K counters) -> 50K padded prefix scan -> direct scatter of
// 8B/edge payloads to final padded slots. L2 absorbs the scattered writes.
// Within-row edge order becomes scatter order (fp32 row-sum reassociation
// only; products identical; 3.2x absmax margin).
//  - spmm + dense chain: bit-identical r20 code (16 lanes/row, fp16x2,
//    uint2 kv, depth-1 kv prefetch, fused final transpose_out).
//  - r21 dual-stream spmm REVERTED (253us regression).
//  - Scaled fp16 state: state_l = xt_l*256^-l, x2^24 at the end.
// Hardening: computed indices clamped (logic error -> absmax fail, not fault).

#define NN 50000
#define NNZ_E 1600000
#define NB (NN * 32)
#define KVCAP 2097152                            // padded kv capacity (need <=1.95M)
#define NNP 50048                                // NN padded to x4 (uint4 zeroing)
#define ROW_NBLK ((NN + 255) / 256)              // 196
#define TIN_BLKS 98                              // transpose-in blocks fused into zero
#define ZBLKS 1024                               // zeroing blocks
#define ZERO_U4 ((2 * KVCAP + 2 * NNP) / 4)      // uint4 count to zero (1073600)

__device__ __forceinline__ int clampi(int v, int hi) {  // [0, hi]
    v = v < 0 ? 0 : v;
    return v > hi ? hi : v;
}

__device__ __forceinline__ unsigned short f2h(float v) {
    union { _Float16 h; unsigned short u; } cv;
    cv.h = (_Float16)v;
    return cv.u;
}

__device__ __forceinline__ float kv_val(unsigned kv) {
    union { unsigned short u; _Float16 h; } cv;
    cv.u = (unsigned short)(kv >> 16);
    return (float)cv.h;
}

// Zero kv buffers + row counters (grid-stride uint4). Blocks >= ZBLKS run the
// fused input transpose (fp32 [B,N] -> fp16 [N,32]); xt16 is not consumed
// until the first spmm, several dispatches later.
__global__ __launch_bounds__(256) void zero_kernel(uint4* __restrict__ z,
                                                   const float* __restrict__ x,
                                                   _Float16* __restrict__ xt) {
    int blk = blockIdx.x, tid = threadIdx.x;
    if (blk >= ZBLKS) {                      // fused transpose_in
        for (int i = (blk - ZBLKS) * 256 + tid; i < NB; i += TIN_BLKS * 256) {
            int n = i >> 5;
            int b = i & 31;
            xt[i] = (_Float16)x[b * NN + n];
        }
        return;
    }
    const uint4 zv = make_uint4(0u, 0u, 0u, 0u);
    for (int i = blk * 256 + tid; i < ZERO_U4; i += ZBLKS * 256) z[i] = zv;
}

// Per-row degree histogram: 1.6M device-scope atomics on 50K L2-resident
// counters (contention ~negligible: avg 32 hits/counter over the pass).
__global__ __launch_bounds__(256) void hist2_kernel(const int* __restrict__ row,
                                                    int* __restrict__ rowcnt) {
    int i = blockIdx.x * 256 + threadIdx.x;
    if (i < NNZ_E) atomicAdd(&rowcnt[clampi(row[i], NN - 1)], 1);
}

// Padded prefix scan over 50K rows, stage 1: per-256-block exclusive scan of
// plen = (cnt+7)&~7 (multiple-of-8 padding); bsum[blk] = block total.
__global__ __launch_bounds__(256) void scanrow_local_kernel(
        const int* __restrict__ rowcnt, int* __restrict__ rowstart,
        int* __restrict__ bsum) {
    __shared__ int s[256];
    int tid = threadIdx.x;
    int i = blockIdx.x * 256 + tid;
    int cnt = (i < NN) ? clampi(rowcnt[i], 2040) : 0;
    int plen = (cnt + 7) & ~7;
    s[tid] = plen;
    __syncthreads();
    for (int off = 1; off < 256; off <<= 1) {
        int t = (tid >= off) ? s[tid - off] : 0;
        __syncthreads();
        s[tid] += t;
        __syncthreads();
    }
    if (i < NN) rowstart[i] = s[tid] - plen;     // exclusive within block
    if (tid == 255) bsum[blockIdx.x] = s[tid];
}

// Stage 2: every block scans the 196 block totals in LDS, adds its prefix,
// writes final rowstart (multiple of 8) and row_desc = start | (niters<<24).
__global__ __launch_bounds__(256) void scanrow_fin_kernel(
        const int* __restrict__ rowcnt, int* __restrict__ rowstart,
        const int* __restrict__ bsum, unsigned* __restrict__ row_desc) {
    __shared__ int s[256];
    int tid = threadIdx.x;
    s[tid] = (tid < ROW_NBLK) ? bsum[tid] : 0;
    __syncthreads();
    for (int off = 1; off < 256; off <<= 1) {
        int t = (tid >= off) ? s[tid - off] : 0;
        __syncthreads();
        s[tid] += t;
        __syncthreads();
    }
    int add = (blockIdx.x > 0) ? s[blockIdx.x - 1] : 0;
    int i = blockIdx.x * 256 + tid;
    if (i < NN) {
        int cnt = clampi(rowcnt[i], 2040);
        int plen = (cnt + 7) & ~7;
        int st = clampi(rowstart[i] + add, KVCAP - 8);
        rowstart[i] = st;
        row_desc[i] = (unsigned)st | ((unsigned)(plen >> 3) << 24);
    }
}

// Direct scatter: each edge claims its slot via a per-row cursor atomic and
// writes both packed kv words. Pad slots remain zero (exact no-op in spmm).
__global__ __launch_bounds__(256) void scatter_kernel(
        const int* __restrict__ row, const int* __restrict__ col,
        const float* __restrict__ a, const float* __restrict__ w,
        const int* __restrict__ rowstart, int* __restrict__ cnt2,
        unsigned* __restrict__ kvA2, unsigned* __restrict__ kvW2) {
    int i = blockIdx.x * 256 + threadIdx.x;
    if (i >= NNZ_E) return;
    int r = clampi(row[i], NN - 1);
    int c = clampi(col[i], NN - 1);
    int q = atomicAdd(&cnt2[r], 1);
    int p = clampi(rowstart[r] + q, KVCAP - 1);
    kvA2[p] = ((unsigned)f2h(a[i]) << 16) | (unsigned)c;
    kvW2[p] = ((unsigned)f2h(w[i]) << 16) | (unsigned)c;
}

// 16 lanes per row; lane l owns batch pair (2l, 2l+1) as one fp16x2 dword.
// 4 rows per wave64 (r15/r20 structure: uniform counted loop over rows
// padded to multiple-of-8 edges, uint2 kv loads, depth-1 kv prefetch, fp32
// accumulation, packed dword store).
// FINAL=1 (last A-pass): writes fp32 out[b*NN+r] = result * 2^24 directly
// (fused transpose_out; skips the intermediate fp16 rounding).
template <int WITH_BIAS, int FINAL>
__global__ __launch_bounds__(256) void spmm_kernel(
        const uint2* __restrict__ kv2, const unsigned* __restrict__ row_desc,
        const unsigned* __restrict__ in32, unsigned* __restrict__ out32,
        const float* __restrict__ bias, float outScale, float biasScale,
        float* __restrict__ outf) {
    int t = blockIdx.x * 256 + threadIdx.x;
    int r = t >> 4;                          // one row per 16 lanes
    int l = t & 15;                          // batch-pair index
    if (r >= NN) return;
    unsigned d = row_desc[r];
    int niter = (int)(d >> 24);
    int base2 = clampi((int)(d & 0xFFFFFFu), KVCAP - 8) >> 1;  // 8-slot aligned
    float accL = 0.0f, accH = 0.0f;          // batch 2l, 2l+1
    uint2 k2[4];
    if (niter > 0) {
#pragma unroll
        for (int q = 0; q < 4; ++q) k2[q] = kv2[base2 + q];
    }
    for (int it = 0; it < niter; ++it) {
        unsigned k[8];
#pragma unroll
        for (int q = 0; q < 4; ++q) { k[2 * q] = k2[q].x; k[2 * q + 1] = k2[q].y; }
        unsigned gd[8];
#pragma unroll
        for (int j = 0; j < 8; ++j) gd[j] = in32[((k[j] & 0xFFFFu) << 4) + l];
        if (it + 1 < niter) {
            int nb2 = base2 + (it + 1) * 4;
#pragma unroll
            for (int q = 0; q < 4; ++q) k2[q] = kv2[nb2 + q];
        }
#pragma unroll
        for (int j = 0; j < 8; ++j) {
            float v = kv_val(k[j]);
            union { unsigned u; _Float16 h[2]; } cv;
            cv.u = gd[j];
            accL += v * (float)cv.h[0];
            accH += v * (float)cv.h[1];
        }
    }
    float rL = accL * outScale, rH = accH * outScale;
    if (WITH_BIAS) {
        float bb = bias[r] * biasScale;
        rL += bb; rH += bb;
    }
    if (FINAL) {
        // fused transpose_out: undo cumulative 256^-3 state scaling (x 2^24)
        outf[(2 * l) * NN + r]     = rL * 16777216.0f;
        outf[(2 * l + 1) * NN + r] = rH * 16777216.0f;
    } else {
        union { unsigned u; _Float16 h[2]; } o;
        o.h[0] = (_Float16)rL;
        o.h[1] = (_Float16)rH;
        out32[(r << 4) + l] = o.u;
    }
}

extern "C" void kernel_launch(void* const* d_in, const int* in_sizes, int n_in,
                              void* d_out, int out_size, void* d_ws, size_t ws_size,
                              hipStream_t stream) {
    const float* x        = (const float*)d_in[0];
    const float* adj_vals = (const float*)d_in[1];
    const float* w_vals   = (const float*)d_in[2];
    const float* bias     = (const float*)d_in[3];
    const int*   row      = (const int*)d_in[4];
    const int*   col      = (const int*)d_in[5];
    float* out = (float*)d_out;

    // Workspace (~24 MB of the 256 MiB ws). Zeroed region must be contiguous:
    // [kvA2 | kvW2 | rowcnt(NNP) | cnt2(NNP)].
    unsigned*  kvA2      = (unsigned*)d_ws;          // KVCAP
    unsigned*  kvW2      = kvA2 + KVCAP;             // KVCAP
    int*       rowcnt    = (int*)(kvW2 + KVCAP);     // NNP (zeroed)
    int*       cnt2      = rowcnt + NNP;             // NNP (zeroed)
    int*       rowstart  = cnt2 + NNP;               // NNP
    int*       bsum      = rowstart + NNP;           // 256
    unsigned*  row_desc  = (unsigned*)(bsum + 256);  // NN
    _Float16*  xt16      = (_Float16*)(row_desc + NN + 8);  // NB fp16
    _Float16*  tmp16     = xt16 + NB;                // NB fp16

    const int BS = 256;
    const int grid_edges = (NNZ_E + BS - 1) / BS;    // 6250
    const int grid_spmm  = (NN * 16 + BS - 1) / BS;  // 3125

    // ---- scatter-sort chain (5 dispatches) ----
    zero_kernel<<<ZBLKS + TIN_BLKS, BS, 0, stream>>>((uint4*)d_ws, x, xt16);
    hist2_kernel<<<grid_edges, BS, 0, stream>>>(row, rowcnt);
    scanrow_local_kernel<<<ROW_NBLK, BS, 0, stream>>>(rowcnt, rowstart, bsum);
    scanrow_fin_kernel<<<ROW_NBLK, BS, 0, stream>>>(rowcnt, rowstart, bsum, row_desc);
    scatter_kernel<<<grid_edges, BS, 0, stream>>>(row, col, adj_vals, w_vals,
                                                  rowstart, cnt2, kvA2, kvW2);

    const uint2* kvA = (const uint2*)kvA2;
    const uint2* kvW = (const uint2*)kvW2;
    const unsigned* xt32  = (const unsigned*)xt16;
    unsigned*       xt32w = (unsigned*)xt16;
    const unsigned* tm32  = (const unsigned*)tmp16;
    unsigned*       tm32w = (unsigned*)tmp16;

    // ---- dense passes (scaled fp16 state: state_l = xt_l * 256^-l) ----
    const float r256 = 1.0f / 256.0f;
    spmm_kernel<0, 0><<<grid_spmm, BS, 0, stream>>>(kvW, row_desc, xt32, tm32w,
                                                    nullptr, 1.0f, 0.0f, nullptr);
    spmm_kernel<1, 0><<<grid_spmm, BS, 0, stream>>>(kvA, row_desc, tm32, xt32w,
                                                    bias, r256, 1.0f / 256.0f, nullptr);
    spmm_kernel<0, 0><<<grid_spmm, BS, 0, stream>>>(kvW, row_desc, xt32, tm32w,
                                                    nullptr, 1.0f, 0.0f, nullptr);
    spmm_kernel<1, 0><<<grid_spmm, BS, 0, stream>>>(kvA, row_desc, tm32, xt32w,
                                                    bias, r256, 1.0f / 65536.0f, nullptr);
    spmm_kernel<0, 0><<<grid_spmm, BS, 0, stream>>>(kvW, row_desc, xt32, tm32w,
                                                    nullptr, 1.0f, 0.0f, nullptr);
    spmm_kernel<1, 1><<<grid_spmm, BS, 0, stream>>>(kvA, row_desc, tm32, xt32w,
                                                    bias, r256, 1.0f / 16777216.0f, out);
}

// Round 8
// 283.211 us; speedup vs baseline: 1.4397x; 1.4397x over previous
//
#include <hip/hip_runtime.h>

// AdultConnectomeNetwork: 3 layers of xt = A_sp @ (W_sp @ xt) + bias.
// Round 23: sort-chain occupancy, r20 spmm untouched. Evidence: r17/18/21
// spmm-invariance => spmm is L2-transaction-bound (structural floor); r22
// scatter => write density matters (8.5x amplification) AND within-bin order
// nondeterminism is tolerated (pass2's LDS cursors were already unordered).
//  - hist/scan granularity DECOUPLED from pass1: hist at 6144-edge chunks
//    (NH=204K, scanfin 1024-slot scan fits), pass1 at 1536-edge chunks
//    (1042 blocks, ~23KB LDS -> 4 resident blocks/CU, was 2). Each pass1
//    block claims its per-bin segment via one global atomicAdd per nonempty
//    bin on the scanned hist cell (claim order nondeterministic - OK).
//  - Bins 128 -> 64 rows (NBIN=782): pass2 LDS 40->23KB, grid 391->782
//    (3 resident blocks/CU, was 1.5).
//  - spmm + dense chain: bit-identical r20 code (16 lanes/row, fp16x2,
//    uint2 kv, depth-1 kv prefetch, fused transposes, scaled fp16 state).
// Hardening: computed indices clamped (logic error -> absmax fail, not fault).

#define NN 50000
#define NNZ_E 1600000
#define NB (NN * 32)
#define CHUNK_H 6144                             // hist chunk
#define NBLK_H ((NNZ_E + CHUNK_H - 1) / CHUNK_H) // 261
#define CHUNK1 1536                              // pass1 chunk (4 per hist chunk)
#define NBLK1P ((NNZ_E + CHUNK1 - 1) / CHUNK1)   // 1042
#define NBIN ((NN + 63) / 64)                    // 782 bins of 64 rows
#define NH (NBIN * NBLK_H)                       // 204102
#define CAP2 2816                                // bin window cap (mean 2046, +17 sigma)
#define BCAP 3328                                // padded per-bin capacity (>=CAP2+7*64)
#define LENP (NBIN * BCAP)                       // 2602496 padded slots
#define SCAN_NBLK ((NH + 255) / 256)             // 798 (<=1024 scanfin slots)
#define TIN_BLKS 98                              // transpose-in blocks fused into hist

__device__ __forceinline__ int clampi(int v, int hi) {  // [0, hi]
    v = v < 0 ? 0 : v;
    return v > hi ? hi : v;
}

__device__ __forceinline__ unsigned short f2h(float v) {
    union { _Float16 h; unsigned short u; } cv;
    cv.h = (_Float16)v;
    return cv.u;
}

__device__ __forceinline__ float kv_val(unsigned kv) {
    union { unsigned short u; _Float16 h; } cv;
    cv.u = (unsigned short)(kv >> 16);
    return (float)cv.h;
}

// Per-(hist-chunk,bin) histogram matrix, bin-major. LDS only. Blocks >=
// NBLK_H run the fused input transpose (fp32 [B,N] -> fp16 [N,32]).
__global__ __launch_bounds__(256) void hist_kernel(const int* __restrict__ row,
                                                   int* __restrict__ hist1,
                                                   const float* __restrict__ x,
                                                   _Float16* __restrict__ xt) {
    __shared__ int h[NBIN];
    int blk = blockIdx.x, tid = threadIdx.x;
    if (blk >= NBLK_H) {                     // fused transpose_in
        for (int i = (blk - NBLK_H) * 256 + tid; i < NB; i += TIN_BLKS * 256) {
            int n = i >> 5;
            int b = i & 31;
            xt[i] = (_Float16)x[b * NN + n];
        }
        return;
    }
    for (int j = tid; j < NBIN; j += 256) h[j] = 0;
    __syncthreads();
    int base = blk * CHUNK_H;
    int n = NNZ_E - base; if (n > CHUNK_H) n = CHUNK_H;
    for (int i = tid; i < n; i += 256)
        atomicAdd(&h[clampi(row[base + i], NN - 1) >> 6], 1);
    __syncthreads();
    for (int j = tid; j < NBIN; j += 256) hist1[j * NBLK_H + blk] = h[j];
}

// Exclusive scan within 256-blocks; bsum[blk] = block total.
__global__ void scan_local_kernel(int* __restrict__ data, int n, int* __restrict__ bsum) {
    __shared__ int s[256];
    int i = blockIdx.x * 256 + threadIdx.x;
    int v = (i < n) ? data[i] : 0;
    s[threadIdx.x] = v;
    __syncthreads();
    for (int off = 1; off < 256; off <<= 1) {
        int t = (threadIdx.x >= off) ? s[threadIdx.x - off] : 0;
        __syncthreads();
        s[threadIdx.x] += t;
        __syncthreads();
    }
    if (i < n) data[i] = s[threadIdx.x] - v;     // exclusive within block
    if (threadIdx.x == 255) bsum[blockIdx.x] = s[threadIdx.x];
}

// Fused top-scan + add + binstart (1024-slot LDS ping-pong scan, 4/thread).
__global__ __launch_bounds__(256) void scanfin_kernel(int* __restrict__ data, int n,
                                                      const int* __restrict__ bsum, int m,
                                                      int* __restrict__ binstart) {
    __shared__ int sa[1024];
    __shared__ int sb[1024];
    int tid = threadIdx.x;
#pragma unroll
    for (int q = 0; q < 4; ++q) {
        int p = tid + q * 256;
        sa[p] = (p < m) ? bsum[p] : 0;
    }
    __syncthreads();
    int* src = sa;
    int* dst = sb;
    for (int off = 1; off < 1024; off <<= 1) {
#pragma unroll
        for (int q = 0; q < 4; ++q) {
            int p = tid + q * 256;
            int v = src[p];
            if (p >= off) v += src[p - off];
            dst[p] = v;
        }
        __syncthreads();
        int* t = src; src = dst; dst = t;
    }
    // src = inclusive scan of bsum
    int add = (blockIdx.x > 0) ? src[blockIdx.x - 1] : 0;
    int i = blockIdx.x * 256 + tid;
    if (i < n) {
        int v = data[i] + add;
        data[i] = v;
        if (i % NBLK_H == 0) binstart[i / NBLK_H] = v;  // i = j*NBLK_H, j < NBIN
    }
    if (i == 0) binstart[NBIN] = NNZ_E;
}

// Pass 1: per-1536-edge-chunk in-LDS bin sort. Block claims its segment of
// each bin's hist-chunk window via ONE global atomicAdd per nonempty bin on
// the scanned hist1 cell (hblk = blk>>2). Payload staged 8B/edge, dense
// burst writes. key = (row<<16)|col.
__global__ __launch_bounds__(256) void pass1_kernel(
        const int* __restrict__ row, const int* __restrict__ col,
        const float* __restrict__ a, const float* __restrict__ w,
        int* __restrict__ hist1_cur,
        unsigned* __restrict__ k1, unsigned* __restrict__ aw1) {
    __shared__ int h[NBIN];                  // local counts -> staging cursors
    __shared__ int hscan[NBIN];              // block-local exclusive scan
    __shared__ int hoff[NBIN];               // claimed global base per bin
    __shared__ int s256[256];
    __shared__ unsigned sKey[CHUNK1];        // 6 KB
    __shared__ unsigned sAW[CHUNK1];         // 6 KB
    int blk = blockIdx.x, tid = threadIdx.x;
    int hblk = blk >> 2;                     // parent hist chunk
    int base = blk * CHUNK1;
    int n = NNZ_E - base; if (n > CHUNK1) n = CHUNK1;

    for (int j = tid; j < NBIN; j += 256) h[j] = 0;
    __syncthreads();
    for (int i = tid; i < n; i += 256)
        atomicAdd(&h[clampi(row[base + i], NN - 1) >> 6], 1);
    __syncthreads();
    int c[4];
    int tsum = 0;
#pragma unroll
    for (int q = 0; q < 4; ++q) {
        int j = tid * 4 + q;
        c[q] = (j < NBIN) ? h[j] : 0;
        tsum += c[q];
    }
    s256[tid] = tsum;
    __syncthreads();
    for (int off = 1; off < 256; off <<= 1) {
        int t = (tid >= off) ? s256[tid - off] : 0;
        __syncthreads();
        s256[tid] += t;
        __syncthreads();
    }
    int ex = s256[tid] - tsum;
    __syncthreads();
    int run = ex;
#pragma unroll
    for (int q = 0; q < 4; ++q) {
        int j = tid * 4 + q;
        if (j < NBIN) {
            hscan[j] = run;
            h[j] = run;                      // staging cursor
            hoff[j] = c[q] ? atomicAdd(&hist1_cur[j * NBLK_H + hblk], c[q]) : 0;
            run += c[q];
        }
    }
    __syncthreads();
    for (int i = tid; i < n; i += 256) {
        int r = clampi(row[base + i], NN - 1);
        int cc = clampi(col[base + i], NN - 1);
        int bin = r >> 6;
        int p = atomicAdd(&h[bin], 1);       // LDS cursor, block-private
        p = clampi(p, n - 1);                // hardening
        sKey[p] = ((unsigned)r << 16) | (unsigned)cc;
        sAW[p] = ((unsigned)f2h(a[base + i]) << 16) | (unsigned)f2h(w[base + i]);
    }
    __syncthreads();
    for (int p = tid; p < n; p += 256) {
        unsigned key = sKey[p];
        int bin = (int)(key >> 22);          // = row >> 6
        int d = clampi(hoff[bin] + (p - hscan[bin]), NNZ_E - 1);
        k1[d] = key;
        aw1[d] = sAW[p];
    }
}

// Pass 2: one block per 64-row bin. Row hist + padded-length scan in LDS,
// emits row_desc[r] = start | (niters<<24) and writes kvA2/kvW2 into the
// bin's fixed 3328-slot window with per-row multiple-of-8 padding (pad kv=0).
__global__ __launch_bounds__(256) void pass2_kernel(
        const unsigned* __restrict__ k1, const unsigned* __restrict__ aw1,
        const int* __restrict__ binstart,
        unsigned* __restrict__ kvA2, unsigned* __restrict__ kvW2,
        unsigned* __restrict__ row_desc) {
    __shared__ unsigned sKey[CAP2];          // 11 KB
    __shared__ unsigned sAW[CAP2];           // 11 KB
    __shared__ int rh[64];
    __shared__ int rs[64];
    __shared__ int cur[64];
    int bin = blockIdx.x, tid = threadIdx.x;
    int r0 = bin << 6;
    int rows = NN - r0; if (rows > 64) rows = 64;
    int base = clampi(binstart[bin], NNZ_E);
    int size = clampi(binstart[bin + 1], NNZ_E) - base;
    size = clampi(size, CAP2);               // hardening (always fits in practice)
    int pbase = bin * BCAP;

    if (tid < 64) rh[tid] = 0;
    __syncthreads();
    for (int i = tid; i < size; i += 256) {
        unsigned key = k1[base + i];
        atomicAdd(&rh[(key >> 16) & 63], 1);
        sKey[i] = key;
        sAW[i] = aw1[base + i];
    }
    __syncthreads();
    int cnt  = (tid < 64) ? rh[tid] : 0;
    int plen = (cnt + 7) & ~7;
    if (tid < 64) rs[tid] = plen;
    __syncthreads();
    for (int off = 1; off < 64; off <<= 1) {
        int t = (tid >= off && tid < 64) ? rs[tid - off] : 0;
        __syncthreads();
        if (tid < 64) rs[tid] += t;
        __syncthreads();
    }
    int rofs = (tid < 64) ? clampi(rs[tid] - plen, BCAP - 8) : 0;
    if (tid < 64) cur[tid] = rofs;
    if (tid < rows)
        row_desc[r0 + tid] = (unsigned)(pbase + rofs) | ((unsigned)(plen >> 3) << 24);
    __syncthreads();
    for (int i = tid; i < size; i += 256) {
        unsigned key = sKey[i];
        unsigned aw  = sAW[i];
        int rl = (key >> 16) & 63;
        int p = atomicAdd(&cur[rl], 1);
        p = clampi(p, BCAP - 1);             // hardening
        unsigned cc = key & 0xFFFFu;
        kvA2[pbase + p] = (aw & 0xFFFF0000u) | cc;
        kvW2[pbase + p] = (aw << 16) | cc;
    }
    __syncthreads();
    if (tid < rows) {
        int pl = (rh[tid] + 7) & ~7;
        for (int q = rh[tid]; q < pl; ++q) {
            int d = clampi(rofs + q, BCAP - 1);
            kvA2[pbase + d] = 0u;
            kvW2[pbase + d] = 0u;
        }
    }
}

// 16 lanes per row; lane l owns batch pair (2l, 2l+1) as one fp16x2 dword.
// 4 rows per wave64 (r15/r20 structure: uniform counted loop over rows
// padded to multiple-of-8 edges, uint2 kv loads, depth-1 kv prefetch, fp32
// accumulation, packed dword store).
// FINAL=1 (last A-pass): writes fp32 out[b*NN+r] = result * 2^24 directly
// (fused transpose_out; skips the intermediate fp16 rounding).
template <int WITH_BIAS, int FINAL>
__global__ __launch_bounds__(256) void spmm_kernel(
        const uint2* __restrict__ kv2, const unsigned* __restrict__ row_desc,
        const unsigned* __restrict__ in32, unsigned* __restrict__ out32,
        const float* __restrict__ bias, float outScale, float biasScale,
        float* __restrict__ outf) {
    int t = blockIdx.x * 256 + threadIdx.x;
    int r = t >> 4;                          // one row per 16 lanes
    int l = t & 15;                          // batch-pair index
    if (r >= NN) return;
    unsigned d = row_desc[r];
    int niter = (int)(d >> 24);
    int base2 = clampi((int)(d & 0xFFFFFFu), LENP - 8) >> 1;  // 8-slot aligned
    float accL = 0.0f, accH = 0.0f;          // batch 2l, 2l+1
    uint2 k2[4];
    if (niter > 0) {
#pragma unroll
        for (int q = 0; q < 4; ++q) k2[q] = kv2[base2 + q];
    }
    for (int it = 0; it < niter; ++it) {
        unsigned k[8];
#pragma unroll
        for (int q = 0; q < 4; ++q) { k[2 * q] = k2[q].x; k[2 * q + 1] = k2[q].y; }
        unsigned gd[8];
#pragma unroll
        for (int j = 0; j < 8; ++j) gd[j] = in32[((k[j] & 0xFFFFu) << 4) + l];
        if (it + 1 < niter) {
            int nb2 = base2 + (it + 1) * 4;
#pragma unroll
            for (int q = 0; q < 4; ++q) k2[q] = kv2[nb2 + q];
        }
#pragma unroll
        for (int j = 0; j < 8; ++j) {
            float v = kv_val(k[j]);
            union { unsigned u; _Float16 h[2]; } cv;
            cv.u = gd[j];
            accL += v * (float)cv.h[0];
            accH += v * (float)cv.h[1];
        }
    }
    float rL = accL * outScale, rH = accH * outScale;
    if (WITH_BIAS) {
        float bb = bias[r] * biasScale;
        rL += bb; rH += bb;
    }
    if (FINAL) {
        // fused transpose_out: undo cumulative 256^-3 state scaling (x 2^24)
        outf[(2 * l) * NN + r]     = rL * 16777216.0f;
        outf[(2 * l + 1) * NN + r] = rH * 16777216.0f;
    } else {
        union { unsigned u; _Float16 h[2]; } o;
        o.h[0] = (_Float16)rL;
        o.h[1] = (_Float16)rH;
        out32[(r << 4) + l] = o.u;
    }
}

extern "C" void kernel_launch(void* const* d_in, const int* in_sizes, int n_in,
                              void* d_out, int out_size, void* d_ws, size_t ws_size,
                              hipStream_t stream) {
    const float* x        = (const float*)d_in[0];
    const float* adj_vals = (const float*)d_in[1];
    const float* w_vals   = (const float*)d_in[2];
    const float* bias     = (const float*)d_in[3];
    const int*   row      = (const int*)d_in[4];
    const int*   col      = (const int*)d_in[5];
    float* out = (float*)d_out;

    // Workspace (~42 MB of the 256 MiB ws)
    unsigned*  k1        = (unsigned*)d_ws;          // NNZ_E (sort keys)
    unsigned*  aw1       = k1 + NNZ_E;               // NNZ_E (packed fp16 a,w)
    unsigned*  kvA2      = aw1 + NNZ_E;              // LENP padded kv (A)
    unsigned*  kvW2      = kvA2 + LENP;              // LENP padded kv (W)
    _Float16*  xt16      = (_Float16*)(kvW2 + LENP); // NB fp16
    _Float16*  tmp16     = xt16 + NB;                // NB fp16
    int*   hist1         = (int*)(tmp16 + NB);       // NH (scanned in place)
    int*   bsumB         = hist1 + NH;               // 1024
    int*   binstart      = bsumB + 1024;             // NBIN+1 (+pad)
    unsigned* row_desc   = (unsigned*)(binstart + NBIN + 8);  // NN

    const int BS = 256;
    const int grid_spmm = (NN * 16 + BS - 1) / BS;   // 3125

    // ---- (chunk,bin) histogram (+fused input transpose) + bin-major scan ----
    hist_kernel<<<NBLK_H + TIN_BLKS, BS, 0, stream>>>(row, hist1, x, xt16);
    scan_local_kernel<<<SCAN_NBLK, BS, 0, stream>>>(hist1, NH, bsumB);
    scanfin_kernel<<<SCAN_NBLK, BS, 0, stream>>>(hist1, NH, bsumB, SCAN_NBLK, binstart);

    // ---- two-pass sort: atomic-claimed bin-group then per-row placement ----
    pass1_kernel<<<NBLK1P, BS, 0, stream>>>(row, col, adj_vals, w_vals,
                                            hist1, k1, aw1);
    pass2_kernel<<<NBIN, BS, 0, stream>>>(k1, aw1, binstart, kvA2, kvW2, row_desc);

    const uint2* kvA = (const uint2*)kvA2;
    const uint2* kvW = (const uint2*)kvW2;
    const unsigned* xt32  = (const unsigned*)xt16;
    unsigned*       xt32w = (unsigned*)xt16;
    const unsigned* tm32  = (const unsigned*)tmp16;
    unsigned*       tm32w = (unsigned*)tmp16;

    // ---- dense passes (scaled fp16 state: state_l = xt_l * 256^-l) ----
    const float r256 = 1.0f / 256.0f;
    spmm_kernel<0, 0><<<grid_spmm, BS, 0, stream>>>(kvW, row_desc, xt32, tm32w,
                                                    nullptr, 1.0f, 0.0f, nullptr);
    spmm_kernel<1, 0><<<grid_spmm, BS, 0, stream>>>(kvA, row_desc, tm32, xt32w,
                                                    bias, r256, 1.0f / 256.0f, nullptr);
    spmm_kernel<0, 0><<<grid_spmm, BS, 0, stream>>>(kvW, row_desc, xt32, tm32w,
                                                    nullptr, 1.0f, 0.0f, nullptr);
    spmm_kernel<1, 0><<<grid_spmm, BS, 0, stream>>>(kvA, row_desc, tm32, xt32w,
                                                    bias, r256, 1.0f / 65536.0f, nullptr);
    spmm_kernel<0, 0><<<grid_spmm, BS, 0, stream>>>(kvW, row_desc, xt32, tm32w,
                                                    nullptr, 1.0f, 0.0f, nullptr);
    spmm_kernel<1, 1><<<grid_spmm, BS, 0, stream>>>(kvA, row_desc, tm32, xt32w,
                                                    bias, r256, 1.0f / 16777216.0f, out);
}

// Round 9
// 246.156 us; speedup vs baseline: 1.6564x; 1.1505x over previous
//
#include <hip/hip_runtime.h>

// AdultConnectomeNetwork: 3 layers of xt = A_sp @ (W_sp @ xt) + bias.
// Round 24: back to r20 geometry (best measured 241us; CHUNK=3072, 391
// 128-row bins). r23's regression isolated the governing law: sort-stage
// time ~ scattered dirty-line count; per-(bin,block) segments must be >=64B
// (r23's 2-edge segments -> 6x write amplification -> 75us pass1).
// Two density/occupancy diffs on top of r20, geometry untouched:
//  1. pass1 payload interleaved: k1+aw1 (2 distant 4B writes/edge) -> one
//     uint2 e1 (1x 8B write/edge): halves dirty lines per segment.
//  2. pass2 de-staged: no sKey/sAW LDS (40KB -> ~1.5KB); histogram loop
//     reads e1, placement loop re-reads e1 from global (bin window 32KB,
//     L2-hot). Occupancy 1.5 -> ~8 blocks/CU, 8B coalesced reads.
//  - spmm + dense chain: bit-identical r20 code (16 lanes/row, fp16x2,
//    uint2 kv, depth-1 kv prefetch, fused transposes, scaled fp16 state).
// Hardening: computed indices clamped (logic error -> absmax fail, not fault).

#define NN 50000
#define NNZ_E 1600000
#define NB (NN * 32)
#define CHUNK 3072
#define NBLK1 ((NNZ_E + CHUNK - 1) / CHUNK)      // 521
#define NBIN ((NN + 127) / 128)                  // 391 bins of 128 rows
#define NH (NBIN * NBLK1)                        // 203711
#define CAP2 5120                                // bin window cap (mean 4092, +16 sigma)
#define BCAP 6144                                // padded per-bin capacity
#define LENP (NBIN * BCAP)                       // 2402304 padded slots
#define SCAN_NBLK ((NH + 255) / 256)             // 796
#define TIN_BLKS 98                              // transpose-in blocks fused into hist

__device__ __forceinline__ int clampi(int v, int hi) {  // [0, hi]
    v = v < 0 ? 0 : v;
    return v > hi ? hi : v;
}

__device__ __forceinline__ unsigned short f2h(float v) {
    union { _Float16 h; unsigned short u; } cv;
    cv.h = (_Float16)v;
    return cv.u;
}

__device__ __forceinline__ float kv_val(unsigned kv) {
    union { unsigned short u; _Float16 h; } cv;
    cv.u = (unsigned short)(kv >> 16);
    return (float)cv.h;
}

// Per-(chunk,bin) histogram matrix, bin-major. LDS only, no global atomics.
// Blocks >= NBLK1 instead run the input transpose (fp32 [B,N] -> fp16 [N,32]).
__global__ __launch_bounds__(256) void hist_kernel(const int* __restrict__ row,
                                                   int* __restrict__ hist1,
                                                   const float* __restrict__ x,
                                                   _Float16* __restrict__ xt) {
    __shared__ int h[NBIN];
    int blk = blockIdx.x, tid = threadIdx.x;
    if (blk >= NBLK1) {                      // fused transpose_in
        for (int i = (blk - NBLK1) * 256 + tid; i < NB; i += TIN_BLKS * 256) {
            int n = i >> 5;
            int b = i & 31;
            xt[i] = (_Float16)x[b * NN + n];
        }
        return;
    }
    for (int j = tid; j < NBIN; j += 256) h[j] = 0;
    __syncthreads();
    int base = blk * CHUNK;
    int n = NNZ_E - base; if (n > CHUNK) n = CHUNK;
    for (int i = tid; i < n; i += 256)
        atomicAdd(&h[clampi(row[base + i], NN - 1) >> 7], 1);
    __syncthreads();
    for (int j = tid; j < NBIN; j += 256) hist1[j * NBLK1 + blk] = h[j];
}

// Exclusive scan within 256-blocks; bsum[blk] = block total.
__global__ void scan_local_kernel(int* __restrict__ data, int n, int* __restrict__ bsum) {
    __shared__ int s[256];
    int i = blockIdx.x * 256 + threadIdx.x;
    int v = (i < n) ? data[i] : 0;
    s[threadIdx.x] = v;
    __syncthreads();
    for (int off = 1; off < 256; off <<= 1) {
        int t = (threadIdx.x >= off) ? s[threadIdx.x - off] : 0;
        __syncthreads();
        s[threadIdx.x] += t;
        __syncthreads();
    }
    if (i < n) data[i] = s[threadIdx.x] - v;     // exclusive within block
    if (threadIdx.x == 255) bsum[blockIdx.x] = s[threadIdx.x];
}

// Fused top-scan + add + binstart (1024-slot LDS ping-pong scan, 4/thread).
__global__ __launch_bounds__(256) void scanfin_kernel(int* __restrict__ data, int n,
                                                      const int* __restrict__ bsum, int m,
                                                      int* __restrict__ binstart) {
    __shared__ int sa[1024];
    __shared__ int sb[1024];
    int tid = threadIdx.x;
#pragma unroll
    for (int q = 0; q < 4; ++q) {
        int p = tid + q * 256;
        sa[p] = (p < m) ? bsum[p] : 0;
    }
    __syncthreads();
    int* src = sa;
    int* dst = sb;
    for (int off = 1; off < 1024; off <<= 1) {
#pragma unroll
        for (int q = 0; q < 4; ++q) {
            int p = tid + q * 256;
            int v = src[p];
            if (p >= off) v += src[p - off];
            dst[p] = v;
        }
        __syncthreads();
        int* t = src; src = dst; dst = t;
    }
    // src = inclusive scan of bsum
    int add = (blockIdx.x > 0) ? src[blockIdx.x - 1] : 0;
    int i = blockIdx.x * 256 + tid;
    if (i < n) {
        int v = data[i] + add;
        data[i] = v;
        if (i % NBLK1 == 0) binstart[i / NBLK1] = v;   // i = j*NBLK1, j < NBIN
    }
    if (i == 0) binstart[NBIN] = NNZ_E;
}

// Pass 1: per-chunk in-LDS bin sort; payload staged 8B/edge, emitted as ONE
// interleaved uint2 {key, aw} per edge (dense full-line burst writes).
// key = (row<<16)|col (both < 2^16).
__global__ __launch_bounds__(256) void pass1_kernel(
        const int* __restrict__ row, const int* __restrict__ col,
        const float* __restrict__ a, const float* __restrict__ w,
        const int* __restrict__ hist1_off,
        uint2* __restrict__ e1) {
    __shared__ int h[NBIN];                  // counts -> placement cursors
    __shared__ int hscan[NBIN];              // block-local exclusive scan
    __shared__ int hoff[NBIN];               // global offsets for (bin, this blk)
    __shared__ int s256[256];
    __shared__ unsigned sKey[CHUNK];         // 12 KB
    __shared__ unsigned sAW[CHUNK];          // 12 KB
    int blk = blockIdx.x, tid = threadIdx.x;
    int base = blk * CHUNK;
    int n = NNZ_E - base; if (n > CHUNK) n = CHUNK;

    for (int j = tid; j < NBIN; j += 256) {
        h[j] = 0;
        hoff[j] = hist1_off[j * NBLK1 + blk];
    }
    __syncthreads();
    for (int i = tid; i < n; i += 256)
        atomicAdd(&h[clampi(row[base + i], NN - 1) >> 7], 1);
    __syncthreads();
    int j0 = tid * 2, j1 = tid * 2 + 1;
    int c0 = (j0 < NBIN) ? h[j0] : 0;
    int c1 = (j1 < NBIN) ? h[j1] : 0;
    int tsum = c0 + c1;
    s256[tid] = tsum;
    __syncthreads();
    for (int off = 1; off < 256; off <<= 1) {
        int t = (tid >= off) ? s256[tid - off] : 0;
        __syncthreads();
        s256[tid] += t;
        __syncthreads();
    }
    int ex = s256[tid] - tsum;
    __syncthreads();
    if (j0 < NBIN) { hscan[j0] = ex;      h[j0] = ex; }
    if (j1 < NBIN) { hscan[j1] = ex + c0; h[j1] = ex + c0; }
    __syncthreads();
    for (int i = tid; i < n; i += 256) {
        int r = clampi(row[base + i], NN - 1);
        int c = clampi(col[base + i], NN - 1);
        int bin = r >> 7;
        int p = atomicAdd(&h[bin], 1);       // LDS cursor, block-private
        p = clampi(p, n - 1);                // hardening
        sKey[p] = ((unsigned)r << 16) | (unsigned)c;
        sAW[p] = ((unsigned)f2h(a[base + i]) << 16) | (unsigned)f2h(w[base + i]);
    }
    __syncthreads();
    for (int p = tid; p < n; p += 256) {
        unsigned key = sKey[p];
        int bin = (int)(key >> 23);          // = row >> 7
        int d = clampi(hoff[bin] + (p - hscan[bin]), NNZ_E - 1);
        e1[d] = make_uint2(key, sAW[p]);     // single 8B interleaved write
    }
}

// Pass 2: one block per 128-row bin, NO LDS staging (r24): loop 1 reads e1
// to build the row histogram; loop 2 re-reads e1 (bin window ~32KB, L2-hot)
// and places edges via per-row LDS cursors. Emits row_desc[r] =
// start | (niters<<24); pads each row to multiple-of-8 slots with kv=0.
__global__ __launch_bounds__(256) void pass2_kernel(
        const uint2* __restrict__ e1, const int* __restrict__ binstart,
        unsigned* __restrict__ kvA2, unsigned* __restrict__ kvW2,
        unsigned* __restrict__ row_desc) {
    __shared__ int rh[128];
    __shared__ int rs[128];
    __shared__ int cur[128];
    int bin = blockIdx.x, tid = threadIdx.x;
    int r0 = bin << 7;
    int rows = NN - r0; if (rows > 128) rows = 128;
    int base = clampi(binstart[bin], NNZ_E);
    int size = clampi(binstart[bin + 1], NNZ_E) - base;
    size = clampi(size, CAP2);               // hardening (always fits in practice)
    int pbase = bin * BCAP;

    if (tid < 128) rh[tid] = 0;
    __syncthreads();
    for (int i = tid; i < size; i += 256)
        atomicAdd(&rh[(e1[base + i].x >> 16) & 127], 1);
    __syncthreads();
    int cnt  = (tid < 128) ? rh[tid] : 0;
    int plen = (cnt + 7) & ~7;
    if (tid < 128) rs[tid] = plen;
    __syncthreads();
    for (int off = 1; off < 128; off <<= 1) {
        int t = (tid >= off && tid < 128) ? rs[tid - off] : 0;
        __syncthreads();
        if (tid < 128) rs[tid] += t;
        __syncthreads();
    }
    int rofs = (tid < 128) ? clampi(rs[tid] - plen, BCAP - 8) : 0;
    if (tid < 128) cur[tid] = rofs;
    if (tid < rows)
        row_desc[r0 + tid] = (unsigned)(pbase + rofs) | ((unsigned)(plen >> 3) << 24);
    __syncthreads();
    for (int i = tid; i < size; i += 256) {
        uint2 e = e1[base + i];              // L2-hot re-read (8B coalesced)
        unsigned key = e.x;
        unsigned aw  = e.y;
        int rl = (key >> 16) & 127;
        int p = atomicAdd(&cur[rl], 1);
        p = clampi(p, BCAP - 1);             // hardening
        unsigned c = key & 0xFFFFu;
        kvA2[pbase + p] = (aw & 0xFFFF0000u) | c;
        kvW2[pbase + p] = (aw << 16) | c;
    }
    __syncthreads();
    if (tid < rows) {
        int pl = (rh[tid] + 7) & ~7;
        for (int q = rh[tid]; q < pl; ++q) {
            int d = clampi(rofs + q, BCAP - 1);
            kvA2[pbase + d] = 0u;
            kvW2[pbase + d] = 0u;
        }
    }
}

// 16 lanes per row; lane l owns batch pair (2l, 2l+1) as one fp16x2 dword.
// 4 rows per wave64 (r15/r20 structure: uniform counted loop over rows
// padded to multiple-of-8 edges, uint2 kv loads, depth-1 kv prefetch, fp32
// accumulation, packed dword store).
// FINAL=1 (last A-pass): writes fp32 out[b*NN+r] = result * 2^24 directly
// (fused transpose_out; skips the intermediate fp16 rounding).
template <int WITH_BIAS, int FINAL>
__global__ __launch_bounds__(256) void spmm_kernel(
        const uint2* __restrict__ kv2, const unsigned* __restrict__ row_desc,
        const unsigned* __restrict__ in32, unsigned* __restrict__ out32,
        const float* __restrict__ bias, float outScale, float biasScale,
        float* __restrict__ outf) {
    int t = blockIdx.x * 256 + threadIdx.x;
    int r = t >> 4;                          // one row per 16 lanes
    int l = t & 15;                          // batch-pair index
    if (r >= NN) return;
    unsigned d = row_desc[r];
    int niter = (int)(d >> 24);
    int base2 = clampi((int)(d & 0xFFFFFFu), LENP - 8) >> 1;  // 8-slot aligned
    float accL = 0.0f, accH = 0.0f;          // batch 2l, 2l+1
    uint2 k2[4];
    if (niter > 0) {
#pragma unroll
        for (int q = 0; q < 4; ++q) k2[q] = kv2[base2 + q];
    }
    for (int it = 0; it < niter; ++it) {
        unsigned k[8];
#pragma unroll
        for (int q = 0; q < 4; ++q) { k[2 * q] = k2[q].x; k[2 * q + 1] = k2[q].y; }
        unsigned gd[8];
#pragma unroll
        for (int j = 0; j < 8; ++j) gd[j] = in32[((k[j] & 0xFFFFu) << 4) + l];
        if (it + 1 < niter) {
            int nb2 = base2 + (it + 1) * 4;
#pragma unroll
            for (int q = 0; q < 4; ++q) k2[q] = kv2[nb2 + q];
        }
#pragma unroll
        for (int j = 0; j < 8; ++j) {
            float v = kv_val(k[j]);
            union { unsigned u; _Float16 h[2]; } cv;
            cv.u = gd[j];
            accL += v * (float)cv.h[0];
            accH += v * (float)cv.h[1];
        }
    }
    float rL = accL * outScale, rH = accH * outScale;
    if (WITH_BIAS) {
        float bb = bias[r] * biasScale;
        rL += bb; rH += bb;
    }
    if (FINAL) {
        // fused transpose_out: undo cumulative 256^-3 state scaling (x 2^24)
        outf[(2 * l) * NN + r]     = rL * 16777216.0f;
        outf[(2 * l + 1) * NN + r] = rH * 16777216.0f;
    } else {
        union { unsigned u; _Float16 h[2]; } o;
        o.h[0] = (_Float16)rL;
        o.h[1] = (_Float16)rH;
        out32[(r << 4) + l] = o.u;
    }
}

extern "C" void kernel_launch(void* const* d_in, const int* in_sizes, int n_in,
                              void* d_out, int out_size, void* d_ws, size_t ws_size,
                              hipStream_t stream) {
    const float* x        = (const float*)d_in[0];
    const float* adj_vals = (const float*)d_in[1];
    const float* w_vals   = (const float*)d_in[2];
    const float* bias     = (const float*)d_in[3];
    const int*   row      = (const int*)d_in[4];
    const int*   col      = (const int*)d_in[5];
    float* out = (float*)d_out;

    // Workspace (~45 MB of the 256 MiB ws)
    uint2*     e1        = (uint2*)d_ws;             // NNZ_E interleaved {key, aw}
    unsigned*  kvA2      = (unsigned*)(e1 + NNZ_E);  // LENP padded kv (A)
    unsigned*  kvW2      = kvA2 + LENP;              // LENP padded kv (W)
    _Float16*  xt16      = (_Float16*)(kvW2 + LENP); // NB fp16
    _Float16*  tmp16     = xt16 + NB;                // NB fp16
    int*   hist1         = (int*)(tmp16 + NB);       // NH (scanned in place)
    int*   bsumB         = hist1 + NH;               // 1024
    int*   binstart      = bsumB + 1024;             // NBIN+1 (+pad)
    unsigned* row_desc   = (unsigned*)(binstart + NBIN + 8);  // NN

    const int BS = 256;
    const int grid_spmm = (NN * 16 + BS - 1) / BS;   // 3125

    // ---- (chunk,bin) histogram (+fused input transpose) + bin-major scan ----
    hist_kernel<<<NBLK1 + TIN_BLKS, BS, 0, stream>>>(row, hist1, x, xt16);
    scan_local_kernel<<<SCAN_NBLK, BS, 0, stream>>>(hist1, NH, bsumB);
    scanfin_kernel<<<SCAN_NBLK, BS, 0, stream>>>(hist1, NH, bsumB, SCAN_NBLK, binstart);

    // ---- two-pass sort: bin-group (interleaved payload) then placement ----
    pass1_kernel<<<NBLK1, BS, 0, stream>>>(row, col, adj_vals, w_vals,
                                           hist1, e1);
    pass2_kernel<<<NBIN, BS, 0, stream>>>(e1, binstart, kvA2, kvW2, row_desc);

    const uint2* kvA = (const uint2*)kvA2;
    const uint2* kvW = (const uint2*)kvW2;
    const unsigned* xt32  = (const unsigned*)xt16;
    unsigned*       xt32w = (unsigned*)xt16;
    const unsigned* tm32  = (const unsigned*)tmp16;
    unsigned*       tm32w = (unsigned*)tmp16;

    // ---- dense passes (scaled fp16 state: state_l = xt_l * 256^-l) ----
    const float r256 = 1.0f / 256.0f;
    spmm_kernel<0, 0><<<grid_spmm, BS, 0, stream>>>(kvW, row_desc, xt32, tm32w,
                                                    nullptr, 1.0f, 0.0f, nullptr);
    spmm_kernel<1, 0><<<grid_spmm, BS, 0, stream>>>(kvA, row_desc, tm32, xt32w,
                                                    bias, r256, 1.0f / 256.0f, nullptr);
    spmm_kernel<0, 0><<<grid_spmm, BS, 0, stream>>>(kvW, row_desc, xt32, tm32w,
                                                    nullptr, 1.0f, 0.0f, nullptr);
    spmm_kernel<1, 0><<<grid_spmm, BS, 0, stream>>>(kvA, row_desc, tm32, xt32w,
                                                    bias, r256, 1.0f / 65536.0f, nullptr);
    spmm_kernel<0, 0><<<grid_spmm, BS, 0, stream>>>(kvW, row_desc, xt32, tm32w,
                                                    nullptr, 1.0f, 0.0f, nullptr);
    spmm_kernel<1, 1><<<grid_spmm, BS, 0, stream>>>(kvA, row_desc, tm32, xt32w,
                                                    bias, r256, 1.0f / 16777216.0f, out);
}

// Round 10
// 235.649 us; speedup vs baseline: 1.7302x; 1.0446x over previous
//
#include <hip/hip_runtime.h>

// AdultConnectomeNetwork: 3 layers of xt = A_sp @ (W_sp @ xt) + bias.
// Round 25: delete the hist+scan chain. The (chunk,bin) histogram + two scan
// dispatches (~25-30us kernel time) existed only to compute pass1's bin base
// offsets. Replaced by fixed-capacity bin windows in e1 + one global
// atomicAdd claim per (block, nonempty bin) on a 391-entry cursor array
// (segment size = CHUNK/NBIN ~ 7.9 edges ~ 63B = r20's proven density; r23's
// failure was 2-edge segments, not claiming). pass2 reads bin size from the
// cursor. 11 -> 9 dispatches; transpose_in rides pass1's grid; cursors
// zeroed by hipMemsetAsync.
// Within-bin order is claim-order-nondeterministic: tolerance established
// (r22 ran fully random within-row order, absmax unchanged at 2048).
//  - spmm + dense chain: bit-identical r20 code (16 lanes/row, fp16x2,
//    uint2 kv, depth-1 kv prefetch, fused transposes, scaled fp16 state).
//  - Sort-density law (r19/r22/r23): scattered segments must be >=64B.
// Hardening: computed indices clamped (logic error -> absmax fail, not fault).

#define NN 50000
#define NNZ_E 1600000
#define NB (NN * 32)
#define CHUNK 3072
#define NBLK1 ((NNZ_E + CHUNK - 1) / CHUNK)      // 521
#define NBIN ((NN + 127) / 128)                  // 391 bins of 128 rows
#define CAP2 5120                                // bin fill cap (mean 4092, +16 sigma)
#define BCAP1 6144                               // e1 window slots per bin
#define LENE (NBIN * BCAP1)                      // 2402304 e1 slots (19.2 MB)
#define BCAP 6144                                // padded kv capacity per bin
#define LENP (NBIN * BCAP)                       // 2402304 padded kv slots
#define TIN_BLKS 98                              // transpose-in blocks fused into pass1

__device__ __forceinline__ int clampi(int v, int hi) {  // [0, hi]
    v = v < 0 ? 0 : v;
    return v > hi ? hi : v;
}

__device__ __forceinline__ unsigned short f2h(float v) {
    union { _Float16 h; unsigned short u; } cv;
    cv.h = (_Float16)v;
    return cv.u;
}

__device__ __forceinline__ float kv_val(unsigned kv) {
    union { unsigned short u; _Float16 h; } cv;
    cv.u = (unsigned short)(kv >> 16);
    return (float)cv.h;
}

// Pass 1: per-chunk in-LDS bin sort; each block claims its segment of each
// bin's fixed window via one global atomicAdd per nonempty bin. Payload
// emitted as interleaved uint2 {key, aw} (8B/edge, ~63B dense segments).
// key = (row<<16)|col. Blocks >= NBLK1 run the fused input transpose.
__global__ __launch_bounds__(256) void pass1_kernel(
        const int* __restrict__ row, const int* __restrict__ col,
        const float* __restrict__ a, const float* __restrict__ w,
        int* __restrict__ cursor, uint2* __restrict__ e1,
        const float* __restrict__ x, _Float16* __restrict__ xt) {
    __shared__ int h[NBIN];                  // counts -> staging cursors
    __shared__ int hscan[NBIN];              // block-local exclusive scan
    __shared__ int hoff[NBIN];               // claimed e1 index per bin
    __shared__ int s256[256];
    __shared__ unsigned sKey[CHUNK];         // 12 KB
    __shared__ unsigned sAW[CHUNK];          // 12 KB
    int blk = blockIdx.x, tid = threadIdx.x;
    if (blk >= NBLK1) {                      // fused transpose_in
        for (int i = (blk - NBLK1) * 256 + tid; i < NB; i += TIN_BLKS * 256) {
            int n = i >> 5;
            int b = i & 31;
            xt[i] = (_Float16)x[b * NN + n];
        }
        return;
    }
    int base = blk * CHUNK;
    int n = NNZ_E - base; if (n > CHUNK) n = CHUNK;

    for (int j = tid; j < NBIN; j += 256) h[j] = 0;
    __syncthreads();
    for (int i = tid; i < n; i += 256)
        atomicAdd(&h[clampi(row[base + i], NN - 1) >> 7], 1);
    __syncthreads();
    int j0 = tid * 2, j1 = tid * 2 + 1;
    int c0 = (j0 < NBIN) ? h[j0] : 0;
    int c1 = (j1 < NBIN) ? h[j1] : 0;
    int tsum = c0 + c1;
    s256[tid] = tsum;
    __syncthreads();
    for (int off = 1; off < 256; off <<= 1) {
        int t = (tid >= off) ? s256[tid - off] : 0;
        __syncthreads();
        s256[tid] += t;
        __syncthreads();
    }
    int ex = s256[tid] - tsum;
    __syncthreads();
    // claim global window segments (one atomic per nonempty bin)
    if (j0 < NBIN) {
        hscan[j0] = ex;
        h[j0] = ex;
        int b0 = c0 ? atomicAdd(&cursor[j0], c0) : 0;
        hoff[j0] = j0 * BCAP1 + clampi(b0, BCAP1 - 1);
    }
    if (j1 < NBIN) {
        hscan[j1] = ex + c0;
        h[j1] = ex + c0;
        int b1 = c1 ? atomicAdd(&cursor[j1], c1) : 0;
        hoff[j1] = j1 * BCAP1 + clampi(b1, BCAP1 - 1);
    }
    __syncthreads();
    for (int i = tid; i < n; i += 256) {
        int r = clampi(row[base + i], NN - 1);
        int c = clampi(col[base + i], NN - 1);
        int bin = r >> 7;
        int p = atomicAdd(&h[bin], 1);       // LDS cursor, block-private
        p = clampi(p, n - 1);                // hardening
        sKey[p] = ((unsigned)r << 16) | (unsigned)c;
        sAW[p] = ((unsigned)f2h(a[base + i]) << 16) | (unsigned)f2h(w[base + i]);
    }
    __syncthreads();
    for (int p = tid; p < n; p += 256) {
        unsigned key = sKey[p];
        int bin = (int)(key >> 23);          // = row >> 7
        int d = clampi(hoff[bin] + (p - hscan[bin]), LENE - 1);
        e1[d] = make_uint2(key, sAW[p]);     // single 8B interleaved write
    }
}

// Pass 2: one block per 128-row bin (size from cursor[bin]); no LDS staging
// (r24): loop 1 reads e1 window to histogram rows, loop 2 re-reads (L2-hot)
// and places via per-row LDS cursors. Emits row_desc[r] = start|(niters<<24);
// pads each row to multiple-of-8 kv slots with kv=0.
__global__ __launch_bounds__(256) void pass2_kernel(
        const uint2* __restrict__ e1, const int* __restrict__ cursor,
        unsigned* __restrict__ kvA2, unsigned* __restrict__ kvW2,
        unsigned* __restrict__ row_desc) {
    __shared__ int rh[128];
    __shared__ int rs[128];
    __shared__ int cur[128];
    int bin = blockIdx.x, tid = threadIdx.x;
    int r0 = bin << 7;
    int rows = NN - r0; if (rows > 128) rows = 128;
    int ebase = bin * BCAP1;
    int size = clampi(cursor[bin], CAP2);    // bin fill (cap: hardening)
    int pbase = bin * BCAP;

    if (tid < 128) rh[tid] = 0;
    __syncthreads();
    for (int i = tid; i < size; i += 256)
        atomicAdd(&rh[(e1[ebase + i].x >> 16) & 127], 1);
    __syncthreads();
    int cnt  = (tid < 128) ? rh[tid] : 0;
    int plen = (cnt + 7) & ~7;
    if (tid < 128) rs[tid] = plen;
    __syncthreads();
    for (int off = 1; off < 128; off <<= 1) {
        int t = (tid >= off && tid < 128) ? rs[tid - off] : 0;
        __syncthreads();
        if (tid < 128) rs[tid] += t;
        __syncthreads();
    }
    int rofs = (tid < 128) ? clampi(rs[tid] - plen, BCAP - 8) : 0;
    if (tid < 128) cur[tid] = rofs;
    if (tid < rows)
        row_desc[r0 + tid] = (unsigned)(pbase + rofs) | ((unsigned)(plen >> 3) << 24);
    __syncthreads();
    for (int i = tid; i < size; i += 256) {
        uint2 e = e1[ebase + i];             // L2-hot re-read (8B coalesced)
        unsigned key = e.x;
        unsigned aw  = e.y;
        int rl = (key >> 16) & 127;
        int p = atomicAdd(&cur[rl], 1);
        p = clampi(p, BCAP - 1);             // hardening
        unsigned c = key & 0xFFFFu;
        kvA2[pbase + p] = (aw & 0xFFFF0000u) | c;
        kvW2[pbase + p] = (aw << 16) | c;
    }
    __syncthreads();
    if (tid < rows) {
        int pl = (rh[tid] + 7) & ~7;
        for (int q = rh[tid]; q < pl; ++q) {
            int d = clampi(rofs + q, BCAP - 1);
            kvA2[pbase + d] = 0u;
            kvW2[pbase + d] = 0u;
        }
    }
}

// 16 lanes per row; lane l owns batch pair (2l, 2l+1) as one fp16x2 dword.
// 4 rows per wave64 (r15/r20 structure: uniform counted loop over rows
// padded to multiple-of-8 edges, uint2 kv loads, depth-1 kv prefetch, fp32
// accumulation, packed dword store).
// FINAL=1 (last A-pass): writes fp32 out[b*NN+r] = result * 2^24 directly
// (fused transpose_out; skips the intermediate fp16 rounding).
template <int WITH_BIAS, int FINAL>
__global__ __launch_bounds__(256) void spmm_kernel(
        const uint2* __restrict__ kv2, const unsigned* __restrict__ row_desc,
        const unsigned* __restrict__ in32, unsigned* __restrict__ out32,
        const float* __restrict__ bias, float outScale, float biasScale,
        float* __restrict__ outf) {
    int t = blockIdx.x * 256 + threadIdx.x;
    int r = t >> 4;                          // one row per 16 lanes
    int l = t & 15;                          // batch-pair index
    if (r >= NN) return;
    unsigned d = row_desc[r];
    int niter = (int)(d >> 24);
    int base2 = clampi((int)(d & 0xFFFFFFu), LENP - 8) >> 1;  // 8-slot aligned
    float accL = 0.0f, accH = 0.0f;          // batch 2l, 2l+1
    uint2 k2[4];
    if (niter > 0) {
#pragma unroll
        for (int q = 0; q < 4; ++q) k2[q] = kv2[base2 + q];
    }
    for (int it = 0; it < niter; ++it) {
        unsigned k[8];
#pragma unroll
        for (int q = 0; q < 4; ++q) { k[2 * q] = k2[q].x; k[2 * q + 1] = k2[q].y; }
        unsigned gd[8];
#pragma unroll
        for (int j = 0; j < 8; ++j) gd[j] = in32[((k[j] & 0xFFFFu) << 4) + l];
        if (it + 1 < niter) {
            int nb2 = base2 + (it + 1) * 4;
#pragma unroll
            for (int q = 0; q < 4; ++q) k2[q] = kv2[nb2 + q];
        }
#pragma unroll
        for (int j = 0; j < 8; ++j) {
            float v = kv_val(k[j]);
            union { unsigned u; _Float16 h[2]; } cv;
            cv.u = gd[j];
            accL += v * (float)cv.h[0];
            accH += v * (float)cv.h[1];
        }
    }
    float rL = accL * outScale, rH = accH * outScale;
    if (WITH_BIAS) {
        float bb = bias[r] * biasScale;
        rL += bb; rH += bb;
    }
    if (FINAL) {
        // fused transpose_out: undo cumulative 256^-3 state scaling (x 2^24)
        outf[(2 * l) * NN + r]     = rL * 16777216.0f;
        outf[(2 * l + 1) * NN + r] = rH * 16777216.0f;
    } else {
        union { unsigned u; _Float16 h[2]; } o;
        o.h[0] = (_Float16)rL;
        o.h[1] = (_Float16)rH;
        out32[(r << 4) + l] = o.u;
    }
}

extern "C" void kernel_launch(void* const* d_in, const int* in_sizes, int n_in,
                              void* d_out, int out_size, void* d_ws, size_t ws_size,
                              hipStream_t stream) {
    const float* x        = (const float*)d_in[0];
    const float* adj_vals = (const float*)d_in[1];
    const float* w_vals   = (const float*)d_in[2];
    const float* bias     = (const float*)d_in[3];
    const int*   row      = (const int*)d_in[4];
    const int*   col      = (const int*)d_in[5];
    float* out = (float*)d_out;

    // Workspace (~45 MB of the 256 MiB ws)
    uint2*     e1        = (uint2*)d_ws;             // LENE windowed {key, aw}
    unsigned*  kvA2      = (unsigned*)(e1 + LENE);   // LENP padded kv (A)
    unsigned*  kvW2      = kvA2 + LENP;              // LENP padded kv (W)
    _Float16*  xt16      = (_Float16*)(kvW2 + LENP); // NB fp16
    _Float16*  tmp16     = xt16 + NB;                // NB fp16
    int*       cursor    = (int*)(tmp16 + NB);       // NBIN bin-fill cursors
    unsigned*  row_desc  = (unsigned*)(cursor + NBIN + 8);  // NN

    const int BS = 256;
    const int grid_spmm = (NN * 16 + BS - 1) / BS;   // 3125

    // ---- single-pass bin grouping (cursor-claimed fixed windows) ----
    hipMemsetAsync(cursor, 0, NBIN * sizeof(int), stream);
    pass1_kernel<<<NBLK1 + TIN_BLKS, BS, 0, stream>>>(row, col, adj_vals, w_vals,
                                                      cursor, e1, x, xt16);
    pass2_kernel<<<NBIN, BS, 0, stream>>>(e1, cursor, kvA2, kvW2, row_desc);

    const uint2* kvA = (const uint2*)kvA2;
    const uint2* kvW = (const uint2*)kvW2;
    const unsigned* xt32  = (const unsigned*)xt16;
    unsigned*       xt32w = (unsigned*)xt16;
    const unsigned* tm32  = (const unsigned*)tmp16;
    unsigned*       tm32w = (unsigned*)tmp16;

    // ---- dense passes (scaled fp16 state: state_l = xt_l * 256^-l) ----
    const float r256 = 1.0f / 256.0f;
    spmm_kernel<0, 0><<<grid_spmm, BS, 0, stream>>>(kvW, row_desc, xt32, tm32w,
                                                    nullptr, 1.0f, 0.0f, nullptr);
    spmm_kernel<1, 0><<<grid_spmm, BS, 0, stream>>>(kvA, row_desc, tm32, xt32w,
                                                    bias, r256, 1.0f / 256.0f, nullptr);
    spmm_kernel<0, 0><<<grid_spmm, BS, 0, stream>>>(kvW, row_desc, xt32, tm32w,
                                                    nullptr, 1.0f, 0.0f, nullptr);
    spmm_kernel<1, 0><<<grid_spmm, BS, 0, stream>>>(kvA, row_desc, tm32, xt32w,
                                                    bias, r256, 1.0f / 65536.0f, nullptr);
    spmm_kernel<0, 0><<<grid_spmm, BS, 0, stream>>>(kvW, row_desc, xt32, tm32w,
                                                    nullptr, 1.0f, 0.0f, nullptr);
    spmm_kernel<1, 1><<<grid_spmm, BS, 0, stream>>>(kvA, row_desc, tm32, xt32w,
                                                    bias, r256, 1.0f / 16777216.0f, out);
}

// Round 11
// 232.997 us; speedup vs baseline: 1.7499x; 1.0114x over previous
//
#include <hip/hip_runtime.h>

// AdultConnectomeNetwork: 3 layers of xt = A_sp @ (W_sp @ xt) + bias.
// Round 26: pass1 internals (top kernel @48.8us, VALUBusy 3.4%, occ 20%).
//  1. Fused transpose_in now LDS-tiled + coalesced (was: 64 lanes touching
//     64 distinct lines per wave, ~102MB line-touches on 98 blocks). 196
//     blocks, tile 256n x 32b (pad-33 fp16), uint4 coalesced stores.
//     Reuses pass1's 24KB staging buffer -> LDS footprint unchanged.
//  2. Vectorized edge loads: int4/float4 on row/col/a/w (all chunks %4==0),
//     edges held in registers across hist->stage (16 -> 4 load instrs per
//     thread-iter, no global re-read in staging).
//  3. Wave-shuffle scan (shfl_up + 4-entry LDS combine): 16 barriers -> 2.
//  - Bin windows + cursor claim (r25), de-staged pass2 (r24), r20 spmm,
//    scaled fp16 state, fused final transpose_out: unchanged.
// Hardening: computed indices clamped (logic error -> absmax fail, not fault).

#define NN 50000
#define NNZ_E 1600000
#define NB (NN * 32)
#define CHUNK 3072
#define NBLK1 ((NNZ_E + CHUNK - 1) / CHUNK)      // 521
#define NBIN ((NN + 127) / 128)                  // 391 bins of 128 rows
#define CAP2 5120                                // bin fill cap (mean 4092, +16 sigma)
#define BCAP1 6144                               // e1 window slots per bin
#define LENE (NBIN * BCAP1)                      // 2402304 e1 slots (19.2 MB)
#define BCAP 6144                                // padded kv capacity per bin
#define LENP (NBIN * BCAP)                       // 2402304 padded kv slots
#define TIN_BLKS 196                             // transpose tiles of 256 n

__device__ __forceinline__ int clampi(int v, int hi) {  // [0, hi]
    v = v < 0 ? 0 : v;
    return v > hi ? hi : v;
}

__device__ __forceinline__ unsigned short f2h(float v) {
    union { _Float16 h; unsigned short u; } cv;
    cv.h = (_Float16)v;
    return cv.u;
}

__device__ __forceinline__ float kv_val(unsigned kv) {
    union { unsigned short u; _Float16 h; } cv;
    cv.u = (unsigned short)(kv >> 16);
    return (float)cv.h;
}

// Pass 1: per-chunk in-LDS bin sort; block claims its segment of each bin's
// fixed window via one global atomicAdd per nonempty bin; payload emitted as
// interleaved uint2 {key, aw}. key = (row<<16)|col. Blocks >= NBLK1 run the
// LDS-tiled coalesced input transpose (fp32 [B,N] -> fp16 [N,32]).
__global__ __launch_bounds__(256) void pass1_kernel(
        const int* __restrict__ row, const int* __restrict__ col,
        const float* __restrict__ a, const float* __restrict__ w,
        int* __restrict__ cursor, uint2* __restrict__ e1,
        const float* __restrict__ x, _Float16* __restrict__ xt) {
    __shared__ int h[NBIN];                  // counts -> staging cursors
    __shared__ int hscan[NBIN];              // block-local exclusive scan
    __shared__ int hoff[NBIN];               // claimed e1 index per bin
    __shared__ int wsum[4];
    __shared__ unsigned sBuf[2 * CHUNK];     // 24 KB: sKey | sAW, or transpose tile
    int blk = blockIdx.x, tid = threadIdx.x;

    if (blk >= NBLK1) {                      // ---- fused coalesced transpose ----
        _Float16* tl = (_Float16*)sBuf;      // [256][33] fp16 tile (16.9 KB)
        int n0 = (blk - NBLK1) * 256;
        int n = n0 + tid;
#pragma unroll 8
        for (int b = 0; b < 32; ++b) {       // coalesced x reads (1KB/wave rows)
            float v = (n < NN) ? x[b * NN + n] : 0.0f;
            tl[tid * 33 + b] = (_Float16)v;
        }
        __syncthreads();
#pragma unroll
        for (int k = 0; k < 4; ++k) {        // coalesced uint4 stores (16B/lane)
            int o = (tid + 256 * k) * 8;     // output offset within tile
            int nl = o >> 5;
            int b0 = o & 31;
            int nn = n0 + nl;
            if (nn < NN) {
                union { uint4 u4; _Float16 hh[8]; } pk;
#pragma unroll
                for (int j = 0; j < 8; ++j) pk.hh[j] = tl[nl * 33 + b0 + j];
                *(uint4*)&xt[nn * 32 + b0] = pk.u4;
            }
        }
        return;
    }

    int base = blk * CHUNK;
    int n = NNZ_E - base; if (n > CHUNK) n = CHUNK;   // 3072 or 2560 (both %4==0)
    int nv = n >> 2;
    unsigned* sKey = sBuf;
    unsigned* sAW  = sBuf + CHUNK;

    for (int j = tid; j < NBIN; j += 256) h[j] = 0;
    __syncthreads();

    // vectorized edge loads; edges stay in registers through staging
    int rr[12], cc[12];
    unsigned aw2[12];
    int ne = 0;
    const int4*   rv4 = (const int4*)row;
    const int4*   cv4 = (const int4*)col;
    const float4* av4 = (const float4*)a;
    const float4* wv4 = (const float4*)w;
    int b4 = base >> 2;
    for (int t4 = tid; t4 < nv; t4 += 256) {
        int4 r = rv4[b4 + t4];
        int4 c = cv4[b4 + t4];
        float4 af = av4[b4 + t4];
        float4 wf = wv4[b4 + t4];
        rr[ne] = r.x; cc[ne] = c.x; aw2[ne] = ((unsigned)f2h(af.x) << 16) | f2h(wf.x); ++ne;
        rr[ne] = r.y; cc[ne] = c.y; aw2[ne] = ((unsigned)f2h(af.y) << 16) | f2h(wf.y); ++ne;
        rr[ne] = r.z; cc[ne] = c.z; aw2[ne] = ((unsigned)f2h(af.z) << 16) | f2h(wf.z); ++ne;
        rr[ne] = r.w; cc[ne] = c.w; aw2[ne] = ((unsigned)f2h(af.w) << 16) | f2h(wf.w); ++ne;
    }
    for (int i = 0; i < ne; ++i)
        atomicAdd(&h[clampi(rr[i], NN - 1) >> 7], 1);
    __syncthreads();

    // exclusive prefix over per-thread (c0+c1) via wave shuffle (2 barriers)
    int j0 = tid * 2, j1 = tid * 2 + 1;
    int c0 = (j0 < NBIN) ? h[j0] : 0;
    int c1 = (j1 < NBIN) ? h[j1] : 0;
    int tsum = c0 + c1;
    int lane = tid & 63, wid = tid >> 6;
    int inc = tsum;
#pragma unroll
    for (int off = 1; off < 64; off <<= 1) {
        int u = __shfl_up(inc, off, 64);
        if (lane >= off) inc += u;
    }
    if (lane == 63) wsum[wid] = inc;
    __syncthreads();                         // also orders h[] reads vs writes below
    int wo = 0;
#pragma unroll
    for (int q = 0; q < 4; ++q) if (q < wid) wo += wsum[q];
    int ex = wo + inc - tsum;

    // claim global window segments (one atomic per nonempty bin)
    if (j0 < NBIN) {
        hscan[j0] = ex;
        h[j0] = ex;
        int b0 = c0 ? atomicAdd(&cursor[j0], c0) : 0;
        hoff[j0] = j0 * BCAP1 + clampi(b0, BCAP1 - 1);
    }
    if (j1 < NBIN) {
        hscan[j1] = ex + c0;
        h[j1] = ex + c0;
        int b1 = c1 ? atomicAdd(&cursor[j1], c1) : 0;
        hoff[j1] = j1 * BCAP1 + clampi(b1, BCAP1 - 1);
    }
    __syncthreads();
    for (int i = 0; i < ne; ++i) {
        int r = clampi(rr[i], NN - 1);
        int c = clampi(cc[i], NN - 1);
        int bin = r >> 7;
        int p = atomicAdd(&h[bin], 1);       // LDS cursor, block-private
        p = clampi(p, n - 1);                // hardening
        sKey[p] = ((unsigned)r << 16) | (unsigned)c;
        sAW[p] = aw2[i];
    }
    __syncthreads();
    for (int p = tid; p < n; p += 256) {
        unsigned key = sKey[p];
        int bin = (int)(key >> 23);          // = row >> 7
        int d = clampi(hoff[bin] + (p - hscan[bin]), LENE - 1);
        e1[d] = make_uint2(key, sAW[p]);     // single 8B interleaved write
    }
}

// Pass 2: one block per 128-row bin (size from cursor[bin]); no LDS staging:
// loop 1 reads e1 window to histogram rows, loop 2 re-reads (L2-hot) and
// places via per-row LDS cursors. Emits row_desc[r] = start|(niters<<24);
// pads each row to multiple-of-8 kv slots with kv=0.
__global__ __launch_bounds__(256) void pass2_kernel(
        const uint2* __restrict__ e1, const int* __restrict__ cursor,
        unsigned* __restrict__ kvA2, unsigned* __restrict__ kvW2,
        unsigned* __restrict__ row_desc) {
    __shared__ int rh[128];
    __shared__ int rs[128];
    __shared__ int cur[128];
    int bin = blockIdx.x, tid = threadIdx.x;
    int r0 = bin << 7;
    int rows = NN - r0; if (rows > 128) rows = 128;
    int ebase = bin * BCAP1;
    int size = clampi(cursor[bin], CAP2);    // bin fill (cap: hardening)
    int pbase = bin * BCAP;

    if (tid < 128) rh[tid] = 0;
    __syncthreads();
    for (int i = tid; i < size; i += 256)
        atomicAdd(&rh[(e1[ebase + i].x >> 16) & 127], 1);
    __syncthreads();
    int cnt  = (tid < 128) ? rh[tid] : 0;
    int plen = (cnt + 7) & ~7;
    if (tid < 128) rs[tid] = plen;
    __syncthreads();
    for (int off = 1; off < 128; off <<= 1) {
        int t = (tid >= off && tid < 128) ? rs[tid - off] : 0;
        __syncthreads();
        if (tid < 128) rs[tid] += t;
        __syncthreads();
    }
    int rofs = (tid < 128) ? clampi(rs[tid] - plen, BCAP - 8) : 0;
    if (tid < 128) cur[tid] = rofs;
    if (tid < rows)
        row_desc[r0 + tid] = (unsigned)(pbase + rofs) | ((unsigned)(plen >> 3) << 24);
    __syncthreads();
    for (int i = tid; i < size; i += 256) {
        uint2 e = e1[ebase + i];             // L2-hot re-read (8B coalesced)
        unsigned key = e.x;
        unsigned aw  = e.y;
        int rl = (key >> 16) & 127;
        int p = atomicAdd(&cur[rl], 1);
        p = clampi(p, BCAP - 1);             // hardening
        unsigned c = key & 0xFFFFu;
        kvA2[pbase + p] = (aw & 0xFFFF0000u) | c;
        kvW2[pbase + p] = (aw << 16) | c;
    }
    __syncthreads();
    if (tid < rows) {
        int pl = (rh[tid] + 7) & ~7;
        for (int q = rh[tid]; q < pl; ++q) {
            int d = clampi(rofs + q, BCAP - 1);
            kvA2[pbase + d] = 0u;
            kvW2[pbase + d] = 0u;
        }
    }
}

// 16 lanes per row; lane l owns batch pair (2l, 2l+1) as one fp16x2 dword.
// 4 rows per wave64 (r15/r20 structure: uniform counted loop over rows
// padded to multiple-of-8 edges, uint2 kv loads, depth-1 kv prefetch, fp32
// accumulation, packed dword store).
// FINAL=1 (last A-pass): writes fp32 out[b*NN+r] = result * 2^24 directly
// (fused transpose_out; skips the intermediate fp16 rounding).
template <int WITH_BIAS, int FINAL>
__global__ __launch_bounds__(256) void spmm_kernel(
        const uint2* __restrict__ kv2, const unsigned* __restrict__ row_desc,
        const unsigned* __restrict__ in32, unsigned* __restrict__ out32,
        const float* __restrict__ bias, float outScale, float biasScale,
        float* __restrict__ outf) {
    int t = blockIdx.x * 256 + threadIdx.x;
    int r = t >> 4;                          // one row per 16 lanes
    int l = t & 15;                          // batch-pair index
    if (r >= NN) return;
    unsigned d = row_desc[r];
    int niter = (int)(d >> 24);
    int base2 = clampi((int)(d & 0xFFFFFFu), LENP - 8) >> 1;  // 8-slot aligned
    float accL = 0.0f, accH = 0.0f;          // batch 2l, 2l+1
    uint2 k2[4];
    if (niter > 0) {
#pragma unroll
        for (int q = 0; q < 4; ++q) k2[q] = kv2[base2 + q];
    }
    for (int it = 0; it < niter; ++it) {
        unsigned k[8];
#pragma unroll
        for (int q = 0; q < 4; ++q) { k[2 * q] = k2[q].x; k[2 * q + 1] = k2[q].y; }
        unsigned gd[8];
#pragma unroll
        for (int j = 0; j < 8; ++j) gd[j] = in32[((k[j] & 0xFFFFu) << 4) + l];
        if (it + 1 < niter) {
            int nb2 = base2 + (it + 1) * 4;
#pragma unroll
            for (int q = 0; q < 4; ++q) k2[q] = kv2[nb2 + q];
        }
#pragma unroll
        for (int j = 0; j < 8; ++j) {
            float v = kv_val(k[j]);
            union { unsigned u; _Float16 h[2]; } cv;
            cv.u = gd[j];
            accL += v * (float)cv.h[0];
            accH += v * (float)cv.h[1];
        }
    }
    float rL = accL * outScale, rH = accH * outScale;
    if (WITH_BIAS) {
        float bb = bias[r] * biasScale;
        rL += bb; rH += bb;
    }
    if (FINAL) {
        // fused transpose_out: undo cumulative 256^-3 state scaling (x 2^24)
        outf[(2 * l) * NN + r]     = rL * 16777216.0f;
        outf[(2 * l + 1) * NN + r] = rH * 16777216.0f;
    } else {
        union { unsigned u; _Float16 h[2]; } o;
        o.h[0] = (_Float16)rL;
        o.h[1] = (_Float16)rH;
        out32[(r << 4) + l] = o.u;
    }
}

extern "C" void kernel_launch(void* const* d_in, const int* in_sizes, int n_in,
                              void* d_out, int out_size, void* d_ws, size_t ws_size,
                              hipStream_t stream) {
    const float* x        = (const float*)d_in[0];
    const float* adj_vals = (const float*)d_in[1];
    const float* w_vals   = (const float*)d_in[2];
    const float* bias     = (const float*)d_in[3];
    const int*   row      = (const int*)d_in[4];
    const int*   col      = (const int*)d_in[5];
    float* out = (float*)d_out;

    // Workspace (~45 MB of the 256 MiB ws)
    uint2*     e1        = (uint2*)d_ws;             // LENE windowed {key, aw}
    unsigned*  kvA2      = (unsigned*)(e1 + LENE);   // LENP padded kv (A)
    unsigned*  kvW2      = kvA2 + LENP;              // LENP padded kv (W)
    _Float16*  xt16      = (_Float16*)(kvW2 + LENP); // NB fp16
    _Float16*  tmp16     = xt16 + NB;                // NB fp16
    int*       cursor    = (int*)(tmp16 + NB);       // NBIN bin-fill cursors
    unsigned*  row_desc  = (unsigned*)(cursor + NBIN + 8);  // NN

    const int BS = 256;
    const int grid_spmm = (NN * 16 + BS - 1) / BS;   // 3125

    // ---- single-pass bin grouping (cursor-claimed fixed windows) ----
    hipMemsetAsync(cursor, 0, NBIN * sizeof(int), stream);
    pass1_kernel<<<NBLK1 + TIN_BLKS, BS, 0, stream>>>(row, col, adj_vals, w_vals,
                                                      cursor, e1, x, xt16);
    pass2_kernel<<<NBIN, BS, 0, stream>>>(e1, cursor, kvA2, kvW2, row_desc);

    const uint2* kvA = (const uint2*)kvA2;
    const uint2* kvW = (const uint2*)kvW2;
    const unsigned* xt32  = (const unsigned*)xt16;
    unsigned*       xt32w = (unsigned*)xt16;
    const unsigned* tm32  = (const unsigned*)tmp16;
    unsigned*       tm32w = (unsigned*)tmp16;

    // ---- dense passes (scaled fp16 state: state_l = xt_l * 256^-l) ----
    const float r256 = 1.0f / 256.0f;
    spmm_kernel<0, 0><<<grid_spmm, BS, 0, stream>>>(kvW, row_desc, xt32, tm32w,
                                                    nullptr, 1.0f, 0.0f, nullptr);
    spmm_kernel<1, 0><<<grid_spmm, BS, 0, stream>>>(kvA, row_desc, tm32, xt32w,
                                                    bias, r256, 1.0f / 256.0f, nullptr);
    spmm_kernel<0, 0><<<grid_spmm, BS, 0, stream>>>(kvW, row_desc, xt32, tm32w,
                                                    nullptr, 1.0f, 0.0f, nullptr);
    spmm_kernel<1, 0><<<grid_spmm, BS, 0, stream>>>(kvA, row_desc, tm32, xt32w,
                                                    bias, r256, 1.0f / 65536.0f, nullptr);
    spmm_kernel<0, 0><<<grid_spmm, BS, 0, stream>>>(kvW, row_desc, xt32, tm32w,
                                                    nullptr, 1.0f, 0.0f, nullptr);
    spmm_kernel<1, 1><<<grid_spmm, BS, 0, stream>>>(kvA, row_desc, tm32, xt32w,
                                                    bias, r256, 1.0f / 16777216.0f, out);
}